// Round 3
// baseline (176.375 us; speedup 1.0000x reference)
//
#include <hip/hip_runtime.h>
#include <math.h>

#define FT_IN  40960
#define FFT_IN 640
#define FT_OUT 256
#define NA     30
#define NSLICE 4          // 64-col slices; fp8 rows = 64 B; ft slice 2.62 MB (L2-resident)
#define BPB    128        // boards per gather block (1024 thr = 128 boards x 8 lanes)

typedef float f32x2 __attribute__((ext_vector_type(2)));

__device__ __forceinline__ unsigned enc4(float a, float b, float c, float d) {
    unsigned r = 0;
    r = __builtin_amdgcn_cvt_pk_fp8_f32(a, b, r, false);   // bytes 0,1
    r = __builtin_amdgcn_cvt_pk_fp8_f32(c, d, r, true);    // bytes 2,3
    return r;
}

// ---------- fused prep: f32 -> fp8 e4m3 sliced convert (ft, fft) + index pack ----------
// sliced layout: [NSLICE][nrows][64 fp8]; one row-slice = 64 B = 4 dwords
__device__ __forceinline__ void conv8_block(const float* __restrict__ src,
                                            uint4* __restrict__ dst,
                                            int nrows, int bid, int tid)
{
    int t = bid * 256 + tid;
    int total = nrows * 16;               // 16 x 16-col chunks per 256-col row
    if (t >= total) return;
    int r = t >> 4, g = t & 15;           // chunk g: cols [16g, 16g+16)
    int s = g >> 2, d = g & 3;            // slice (64 cols = 4 chunks), uint4-within-row
    const float4* sp = (const float4*)(src + (size_t)r * FT_OUT + g * 16);
    float4 v0 = sp[0], v1 = sp[1], v2 = sp[2], v3 = sp[3];
    uint4 u;
    u.x = enc4(v0.x, v0.y, v0.z, v0.w);
    u.y = enc4(v1.x, v1.y, v1.z, v1.w);
    u.z = enc4(v2.x, v2.y, v2.z, v2.w);
    u.w = enc4(v3.x, v3.y, v3.z, v3.w);
    dst[((size_t)s * nrows + r) * 4 + d] = u;
}

__global__ __launch_bounds__(256) void prep(
    const float* __restrict__ ft_w, const float* __restrict__ fft_w,
    const int* __restrict__ stm, const int* __restrict__ nstm,
    const int* __restrict__ fstm, const int* __restrict__ fnstm,
    uint4* __restrict__ ft_o, uint4* __restrict__ fft_o,
    uint2* __restrict__ pidx, float* __restrict__ acc, unsigned* __restrict__ cnt,
    int n_boards, int nb_ft, int nb_fft)
{
    int bid = blockIdx.x;
    if (bid < nb_ft) {
        conv8_block(ft_w, ft_o, FT_IN, bid, threadIdx.x);
    } else if (bid < nb_ft + nb_fft) {
        conv8_block(fft_w, fft_o, FFT_IN, bid - nb_ft, threadIdx.x);
    } else {
        int t = (bid - nb_ft - nb_fft) * 256 + (int)threadIdx.x;
        int total = n_boards * NA;
        if (t < total) {
            // natural [board][a] layout: pure streaming copy, coalesced both ends
            uint2 v;
            v.x = (unsigned)stm[t]  | ((unsigned)nstm[t]  << 16);
            v.y = (unsigned)fstm[t] | ((unsigned)fnstm[t] << 16);
            pidx[t] = v;
        }
        // ws is poisoned every call: zero the accumulator + completion counter here
        if (t < n_boards)       acc[t] = 0.f;
        else if (t == n_boards) *cnt = 0u;
    }
}

// ---------- gather v4: hybrid loads + fused final (last-block reduction) ----------
// 1024 thr = 128 boards x 8 lanes. Lane ql: side = ql>>2 (0=stm,1=nstm),
// c = ql&3 (16B chunk of this side's 64B row-slice).
// Per iter per lane: ONE 16B global load (ft, L2-resident slice) + ONE 16B LDS
// read (fft, rotated uint4 layout). Per-board partials go to a device-coherent
// accumulator via atomicAdd; the last block to finish (device-scope counter)
// applies sigmoid and writes out — removes the nnue_final dispatch and the
// partial-buffer round-trip.
__global__ __launch_bounds__(1024, 8) void nnue_gather(
    const uint2* __restrict__ pidx,      // [n_boards][NA] packed ushort4
    const char* __restrict__ ft, const char* __restrict__ fft,
    const float* __restrict__ ft_b, const float* __restrict__ fft_b,
    const float* __restrict__ out_w, const float* __restrict__ out_b,
    float* __restrict__ acc, unsigned* __restrict__ cnt,
    float* __restrict__ out, int n_boards)
{
    extern __shared__ char smem[];
    uint2* lidx = (uint2*)smem;                     // [BPB][NA] = 30720 B
    uint4* lf4  = (uint4*)(smem + NA * BPB * 8);    // [FFT_IN][4] rotated = 40960 B
    const int slice = blockIdx.x & (NSLICE - 1);
    const int group = blockIdx.x >> 2;
    const int tid = (int)threadIdx.x;

    {   // stage this group's indices: one contiguous 30 KB block copy
        const uint2* psrc = pidx + (size_t)group * BPB * NA;
        int lim = (n_boards - group * BPB) * NA;    // guard for ragged tail
        if (lim > NA * BPB) lim = NA * BPB;
        for (int i = tid; i < NA * BPB; i += 1024)
            lidx[i] = (i < lim) ? psrc[i] : uint2{0u, 0u};
    }
    {   // stage fft fp8 slice; uint4 chunk c of row r stored at slot ((c+r)&3)
        const uint4* fsrc = (const uint4*)(fft + (size_t)slice * FFT_IN * 64);
        for (int i = tid; i < FFT_IN * 4; i += 1024) {
            int r = i >> 2, c = i & 3;
            lf4[(r << 2) + ((c + r) & 3)] = fsrc[i];
        }
    }
    __syncthreads();

    const int sub  = tid >> 3;            // board within block
    const int ql   = tid & 7;             // lane within board
    const int side = ql >> 2;             // 0 = stm lanes, 1 = nstm lanes
    const int c    = ql & 3;              // 16B chunk within 64B row-slice
    const unsigned shf = (unsigned)side << 4;
    const int board = group * BPB + sub;
    const bool active = board < n_boards;

    const char* ftS = ft + (size_t)slice * FT_IN * 64 + c * 16;
    const int col = slice * 64 + c * 16;

    f32x2 a8[8];
    #pragma unroll
    for (int i = 0; i < 8; ++i) a8[i] = f32x2{0.f, 0.f};

    const uint2* myidx = lidx + sub * NA;

    #pragma unroll
    for (int a = 0; a < NA; ++a) {
        uint2 iv = myidx[a];                        // broadcast across 8 lanes
        unsigned rx = (iv.x >> shf) & 0xFFFFu;      // ft row for this side
        unsigned ry = (iv.y >> shf) & 0xFFFFu;      // fft row for this side
        uint4 u = *(const uint4*)(ftS + ((size_t)rx << 6));
        uint4 g = lf4[(ry << 2) + ((c + ry) & 3)];
        a8[0] += __builtin_amdgcn_cvt_pk_f32_fp8(u.x, false);
        a8[1] += __builtin_amdgcn_cvt_pk_f32_fp8(u.x, true);
        a8[2] += __builtin_amdgcn_cvt_pk_f32_fp8(u.y, false);
        a8[3] += __builtin_amdgcn_cvt_pk_f32_fp8(u.y, true);
        a8[4] += __builtin_amdgcn_cvt_pk_f32_fp8(u.z, false);
        a8[5] += __builtin_amdgcn_cvt_pk_f32_fp8(u.z, true);
        a8[6] += __builtin_amdgcn_cvt_pk_f32_fp8(u.w, false);
        a8[7] += __builtin_amdgcn_cvt_pk_f32_fp8(u.w, true);
        a8[0] += __builtin_amdgcn_cvt_pk_f32_fp8(g.x, false);
        a8[1] += __builtin_amdgcn_cvt_pk_f32_fp8(g.x, true);
        a8[2] += __builtin_amdgcn_cvt_pk_f32_fp8(g.y, false);
        a8[3] += __builtin_amdgcn_cvt_pk_f32_fp8(g.y, true);
        a8[4] += __builtin_amdgcn_cvt_pk_f32_fp8(g.z, false);
        a8[5] += __builtin_amdgcn_cvt_pk_f32_fp8(g.z, true);
        a8[6] += __builtin_amdgcn_cvt_pk_f32_fp8(g.w, false);
        a8[7] += __builtin_amdgcn_cvt_pk_f32_fp8(g.w, true);
    }

    // epilogue: f32 bias + clip + partial dot (this lane covers 16 cols of its side)
    float h[16];
    #pragma unroll
    for (int i = 0; i < 8; ++i) { h[2*i] = a8[i].x; h[2*i+1] = a8[i].y; }
    const float4* bf = (const float4*)(ft_b  + col);
    const float4* bg = (const float4*)(fft_b + col);
    const float4* wp = (const float4*)(out_w + side * FT_OUT + col);
    float p = 0.f;
    #pragma unroll
    for (int q = 0; q < 4; ++q) {
        float4 b = bf[q], gq = bg[q], w = wp[q];
        p += fminf(fmaxf(h[4*q+0] + b.x + gq.x, 0.f), 1.f) * w.x;
        p += fminf(fmaxf(h[4*q+1] + b.y + gq.y, 0.f), 1.f) * w.y;
        p += fminf(fmaxf(h[4*q+2] + b.z + gq.z, 0.f), 1.f) * w.z;
        p += fminf(fmaxf(h[4*q+3] + b.w + gq.w, 0.f), 1.f) * w.w;
    }
    p += __shfl_xor(p, 1, 64);
    p += __shfl_xor(p, 2, 64);
    p += __shfl_xor(p, 4, 64);
    if (active && ql == 0)
        atomicAdd(acc + board, p);                  // device-scope, XCD-coherent

    // ---- last-block fused final: sigmoid over the completed accumulator ----
    __shared__ unsigned winner;
    __syncthreads();                                // all this block's adds issued+drained
    if (tid == 0) {
        __threadfence();                            // release: adds visible before count
        winner = (atomicAdd(cnt, 1u) == (unsigned)(gridDim.x - 1)) ? 1u : 0u;
    }
    __syncthreads();
    if (winner) {
        __threadfence();                            // acquire side
        const float ob = out_b[0];
        for (int b = tid; b < n_boards; b += 1024) {
            // coherent (agent-scope) load: safe against stale per-XCD L2 lines
            float zv = ob + __hip_atomic_load(acc + b, __ATOMIC_RELAXED,
                                              __HIP_MEMORY_SCOPE_AGENT);
            out[b] = 1.0f / (1.0f + expf(-zv));
        }
    }
}

// ---------- fallback: direct f32 gather (if ws too small) ----------
__global__ __launch_bounds__(256) void nnue_fwd_direct(
    const int* __restrict__ stm_idx, const int* __restrict__ nstm_idx,
    const int* __restrict__ f_stm_idx, const int* __restrict__ f_nstm_idx,
    const float* __restrict__ ft_w, const float* __restrict__ ft_b,
    const float* __restrict__ fft_w, const float* __restrict__ fft_b,
    const float* __restrict__ out_w, const float* __restrict__ out_b,
    float* __restrict__ out, int n_boards)
{
    const int board = (int)((blockIdx.x * blockDim.x + threadIdx.x) >> 6);
    const int lane  = (int)(threadIdx.x & 63);
    if (board >= n_boards) return;
    const int col = lane << 2;
    const float4 ftb  = *(const float4*)(ft_b  + col);
    const float4 fftb = *(const float4*)(fft_b + col);
    float a0x = ftb.x + fftb.x, a0y = ftb.y + fftb.y,
          a0z = ftb.z + fftb.z, a0w = ftb.w + fftb.w;
    float a1x = a0x, a1y = a0y, a1z = a0z, a1w = a0w;
    const int* si  = stm_idx    + (size_t)board * NA;
    const int* ni  = nstm_idx   + (size_t)board * NA;
    const int* fsi = f_stm_idx  + (size_t)board * NA;
    const int* fni = f_nstm_idx + (size_t)board * NA;
    #pragma unroll 5
    for (int a = 0; a < NA; ++a) {
        const float4 r0 = *(const float4*)(ft_w  + (size_t)si[a]  * FT_OUT + col);
        const float4 r1 = *(const float4*)(ft_w  + (size_t)ni[a]  * FT_OUT + col);
        const float4 r2 = *(const float4*)(fft_w + (size_t)fsi[a] * FT_OUT + col);
        const float4 r3 = *(const float4*)(fft_w + (size_t)fni[a] * FT_OUT + col);
        a0x += r0.x + r2.x; a0y += r0.y + r2.y; a0z += r0.z + r2.z; a0w += r0.w + r2.w;
        a1x += r1.x + r3.x; a1y += r1.y + r3.y; a1z += r1.z + r3.z; a1w += r1.w + r3.w;
    }
    a0x = fminf(fmaxf(a0x, 0.f), 1.f); a0y = fminf(fmaxf(a0y, 0.f), 1.f);
    a0z = fminf(fmaxf(a0z, 0.f), 1.f); a0w = fminf(fmaxf(a0w, 0.f), 1.f);
    a1x = fminf(fmaxf(a1x, 0.f), 1.f); a1y = fminf(fmaxf(a1y, 0.f), 1.f);
    a1z = fminf(fmaxf(a1z, 0.f), 1.f); a1w = fminf(fmaxf(a1w, 0.f), 1.f);
    const float4 w0 = *(const float4*)(out_w + col);
    const float4 w1 = *(const float4*)(out_w + FT_OUT + col);
    float p = a0x * w0.x + a0y * w0.y + a0z * w0.z + a0w * w0.w
            + a1x * w1.x + a1y * w1.y + a1z * w1.z + a1w * w1.w;
    #pragma unroll
    for (int off = 32; off > 0; off >>= 1) p += __shfl_down(p, off, 64);
    if (lane == 0) out[board] = 1.0f / (1.0f + expf(-(p + out_b[0])));
}

extern "C" void kernel_launch(void* const* d_in, const int* in_sizes, int n_in,
                              void* d_out, int out_size, void* d_ws, size_t ws_size,
                              hipStream_t stream) {
    const int*   stm_idx    = (const int*)d_in[0];
    const int*   nstm_idx   = (const int*)d_in[1];
    const int*   f_stm_idx  = (const int*)d_in[2];
    const int*   f_nstm_idx = (const int*)d_in[3];
    const float* ft_w  = (const float*)d_in[4];
    const float* ft_b  = (const float*)d_in[5];
    const float* fft_w = (const float*)d_in[6];
    const float* fft_b = (const float*)d_in[7];
    const float* out_w = (const float*)d_in[8];
    const float* out_b = (const float*)d_in[9];
    float* out = (float*)d_out;

    const int n_boards = in_sizes[0] / NA;

    const size_t ft_bytes   = (size_t)FT_IN  * FT_OUT;                   // 10.49 MB fp8
    const size_t fft_bytes  = (size_t)FFT_IN * FT_OUT;                   // 160 KB fp8
    const size_t pidx_bytes = (size_t)n_boards * NA * sizeof(uint2);     // 3.93 MB
    const size_t acc_bytes  = (size_t)n_boards * sizeof(float) + 64;     // 64 KB + cnt
    const size_t need = ft_bytes + fft_bytes + pidx_bytes + acc_bytes;

    const size_t lds_bytes = (size_t)NA * BPB * 8 + (size_t)FFT_IN * 64; // 71680

    bool ok = (ws_size >= need);
    if (ok) {
        ok = (hipFuncSetAttribute((const void*)nnue_gather,
                                  hipFuncAttributeMaxDynamicSharedMemorySize,
                                  (int)lds_bytes) == hipSuccess);
    }
    if (!ok) {
        const int grid = (n_boards + 3) / 4;
        nnue_fwd_direct<<<grid, 256, 0, stream>>>(stm_idx, nstm_idx, f_stm_idx, f_nstm_idx,
                                                  ft_w, ft_b, fft_w, fft_b, out_w, out_b,
                                                  out, n_boards);
        return;
    }

    char* wsp = (char*)d_ws;
    uint4*    ws_ft   = (uint4*)wsp;            wsp += ft_bytes;
    uint4*    ws_fft  = (uint4*)wsp;            wsp += fft_bytes;
    uint2*    ws_pidx = (uint2*)wsp;            wsp += pidx_bytes;
    float*    ws_acc  = (float*)wsp;            wsp += (size_t)n_boards * sizeof(float);
    unsigned* ws_cnt  = (unsigned*)wsp;

    {   // fused prep: fp8 converts + index pack + acc/cnt zeroing in one dispatch
        const int nb_ft   = FT_IN  * 16 / 256;               // 2560
        const int nb_fft  = FFT_IN * 16 / 256;               // 40
        const int nb_pack = (n_boards * NA + 255) / 256;
        prep<<<nb_ft + nb_fft + nb_pack, 256, 0, stream>>>(
            ft_w, fft_w, stm_idx, nstm_idx, f_stm_idx, f_nstm_idx,
            ws_ft, ws_fft, ws_pidx, ws_acc, ws_cnt, n_boards, nb_ft, nb_fft);
    }
    {   // sliced gather + fused final: last finishing block applies sigmoid
        int groups = (n_boards + BPB - 1) / BPB;
        nnue_gather<<<groups * NSLICE, 1024, lds_bytes, stream>>>(
            (const uint2*)ws_pidx, (const char*)ws_ft, (const char*)ws_fft,
            ft_b, fft_b, out_w, out_b, ws_acc, ws_cnt, out, n_boards);
    }
}

// Round 4
// 128.434 us; speedup vs baseline: 1.3733x; 1.3733x over previous
//
#include <hip/hip_runtime.h>
#include <math.h>

#define FT_IN  40960
#define FFT_IN 640
#define FT_OUT 256
#define NA     30
#define NSLICE 4          // 64-col slices; fp8 rows = 64 B; ft slice 2.62 MB (L2-resident)
#define BPB    128        // boards per gather block (1024 thr = 128 boards x 8 lanes)

typedef float f32x2 __attribute__((ext_vector_type(2)));

__device__ __forceinline__ unsigned enc4(float a, float b, float c, float d) {
    unsigned r = 0;
    r = __builtin_amdgcn_cvt_pk_fp8_f32(a, b, r, false);   // bytes 0,1
    r = __builtin_amdgcn_cvt_pk_fp8_f32(c, d, r, true);    // bytes 2,3
    return r;
}

// ---------- fused prep: f32 -> fp8 e4m3 sliced convert (ft, fft) + index pack ----------
// sliced layout: [NSLICE][nrows][64 fp8]; one row-slice = 64 B = 4 dwords
__device__ __forceinline__ void conv8_block(const float* __restrict__ src,
                                            uint4* __restrict__ dst,
                                            int nrows, int bid, int tid)
{
    int t = bid * 256 + tid;
    int total = nrows * 16;               // 16 x 16-col chunks per 256-col row
    if (t >= total) return;
    int r = t >> 4, g = t & 15;           // chunk g: cols [16g, 16g+16)
    int s = g >> 2, d = g & 3;            // slice (64 cols = 4 chunks), uint4-within-row
    const float4* sp = (const float4*)(src + (size_t)r * FT_OUT + g * 16);
    float4 v0 = sp[0], v1 = sp[1], v2 = sp[2], v3 = sp[3];
    uint4 u;
    u.x = enc4(v0.x, v0.y, v0.z, v0.w);
    u.y = enc4(v1.x, v1.y, v1.z, v1.w);
    u.z = enc4(v2.x, v2.y, v2.z, v2.w);
    u.w = enc4(v3.x, v3.y, v3.z, v3.w);
    dst[((size_t)s * nrows + r) * 4 + d] = u;
}

__global__ __launch_bounds__(256) void prep(
    const float* __restrict__ ft_w, const float* __restrict__ fft_w,
    const int* __restrict__ stm, const int* __restrict__ nstm,
    const int* __restrict__ fstm, const int* __restrict__ fnstm,
    uint4* __restrict__ ft_o, uint4* __restrict__ fft_o,
    uint2* __restrict__ pidx, int n_boards, int nb_ft, int nb_fft)
{
    int bid = blockIdx.x;
    if (bid < nb_ft) {
        conv8_block(ft_w, ft_o, FT_IN, bid, threadIdx.x);
    } else if (bid < nb_ft + nb_fft) {
        conv8_block(fft_w, fft_o, FFT_IN, bid - nb_ft, threadIdx.x);
    } else {
        int t = (bid - nb_ft - nb_fft) * 256 + (int)threadIdx.x;
        int total = n_boards * NA;
        if (t < total) {
            // natural [board][a] layout: pure streaming copy, coalesced both ends
            uint2 v;
            v.x = (unsigned)stm[t]  | ((unsigned)nstm[t]  << 16);
            v.y = (unsigned)fstm[t] | ((unsigned)fnstm[t] << 16);
            pidx[t] = v;
        }
    }
}

// ---------- gather v5: hybrid loads + depth-4 software prefetch ----------
// 1024 thr = 128 boards x 8 lanes. Lane ql: side = ql>>2 (0=stm,1=nstm),
// c = ql&3 (16B chunk of this side's 64B row-slice).
// Round-3 counters (identical loop body): HBM 3%, VALUBusy 24%, 0 bank
// conflicts -> latency-bound, ~1 L2 load in flight per wave (VGPR_Count=32).
// Fix: rolling 4-deep prefetch of the ft uint4 loads so the ~200cy L2-hit
// latency overlaps 4 iterations of VALU (64cy each). Register budget:
// a8(16) + u[4](16) + ryq(4) + misc ~= 50 VGPR < the 64 cap of (1024,8),
// so occupancy stays 2 blocks/CU = 32 waves/CU.
// NO device-scope atomics/fences anywhere (round-3 lesson: per-block
// __threadfence + atomics poison the L2-resident ft slice, -45 us).
__global__ __launch_bounds__(1024, 8) void nnue_gather(
    const uint2* __restrict__ pidx,      // [n_boards][NA] packed ushort4
    const char* __restrict__ ft, const char* __restrict__ fft,
    const float* __restrict__ ft_b, const float* __restrict__ fft_b,
    const float* __restrict__ out_w, float* __restrict__ partial, int n_boards)
{
    extern __shared__ char smem[];
    uint2* lidx = (uint2*)smem;                     // [BPB][NA] = 30720 B
    uint4* lf4  = (uint4*)(smem + NA * BPB * 8);    // [FFT_IN][4] rotated = 40960 B
    const int slice = blockIdx.x & (NSLICE - 1);
    const int group = blockIdx.x >> 2;
    const int tid = (int)threadIdx.x;

    {   // stage this group's indices: one contiguous 30 KB block copy
        const uint2* psrc = pidx + (size_t)group * BPB * NA;
        int lim = (n_boards - group * BPB) * NA;    // guard for ragged tail
        if (lim > NA * BPB) lim = NA * BPB;
        for (int i = tid; i < NA * BPB; i += 1024)
            lidx[i] = (i < lim) ? psrc[i] : uint2{0u, 0u};
    }
    {   // stage fft fp8 slice; uint4 chunk c of row r stored at slot ((c+r)&3)
        const uint4* fsrc = (const uint4*)(fft + (size_t)slice * FFT_IN * 64);
        for (int i = tid; i < FFT_IN * 4; i += 1024) {
            int r = i >> 2, c = i & 3;
            lf4[(r << 2) + ((c + r) & 3)] = fsrc[i];
        }
    }
    __syncthreads();

    const int sub  = tid >> 3;            // board within block
    const int ql   = tid & 7;             // lane within board
    const int side = ql >> 2;             // 0 = stm lanes, 1 = nstm lanes
    const int c    = ql & 3;              // 16B chunk within 64B row-slice
    const unsigned shf = (unsigned)side << 4;
    const int board = group * BPB + sub;
    const bool active = board < n_boards;

    const char* ftS = ft + (size_t)slice * FT_IN * 64 + c * 16;
    const int col = slice * 64 + c * 16;

    f32x2 a8[8];
    #pragma unroll
    for (int i = 0; i < 8; ++i) a8[i] = f32x2{0.f, 0.f};

    const uint2* myidx = lidx + sub * NA;

    // ---- depth-4 rolling prefetch pipeline ----
    uint4 u[4];
    unsigned ryq[4];
    #pragma unroll
    for (int i = 0; i < 4; ++i) {
        uint2 iv = myidx[i];
        u[i]   = *(const uint4*)(ftS + ((size_t)((iv.x >> shf) & 0xFFFFu) << 6));
        ryq[i] = (iv.y >> shf) & 0xFFFFu;
    }

    #pragma unroll
    for (int a = 0; a < NA; ++a) {
        uint4 uc    = u[a & 3];             // issued 4 iterations ago
        unsigned ry = ryq[a & 3];
        if (a + 4 < NA) {                   // refill the pipeline slot
            uint2 iv = myidx[a + 4];
            u[a & 3]   = *(const uint4*)(ftS + ((size_t)((iv.x >> shf) & 0xFFFFu) << 6));
            ryq[a & 3] = (iv.y >> shf) & 0xFFFFu;
        }
        uint4 g = lf4[(ry << 2) + ((c + ry) & 3)];
        a8[0] += __builtin_amdgcn_cvt_pk_f32_fp8(uc.x, false);
        a8[1] += __builtin_amdgcn_cvt_pk_f32_fp8(uc.x, true);
        a8[2] += __builtin_amdgcn_cvt_pk_f32_fp8(uc.y, false);
        a8[3] += __builtin_amdgcn_cvt_pk_f32_fp8(uc.y, true);
        a8[4] += __builtin_amdgcn_cvt_pk_f32_fp8(uc.z, false);
        a8[5] += __builtin_amdgcn_cvt_pk_f32_fp8(uc.z, true);
        a8[6] += __builtin_amdgcn_cvt_pk_f32_fp8(uc.w, false);
        a8[7] += __builtin_amdgcn_cvt_pk_f32_fp8(uc.w, true);
        a8[0] += __builtin_amdgcn_cvt_pk_f32_fp8(g.x, false);
        a8[1] += __builtin_amdgcn_cvt_pk_f32_fp8(g.x, true);
        a8[2] += __builtin_amdgcn_cvt_pk_f32_fp8(g.y, false);
        a8[3] += __builtin_amdgcn_cvt_pk_f32_fp8(g.y, true);
        a8[4] += __builtin_amdgcn_cvt_pk_f32_fp8(g.z, false);
        a8[5] += __builtin_amdgcn_cvt_pk_f32_fp8(g.z, true);
        a8[6] += __builtin_amdgcn_cvt_pk_f32_fp8(g.w, false);
        a8[7] += __builtin_amdgcn_cvt_pk_f32_fp8(g.w, true);
    }

    // epilogue: f32 bias + clip + partial dot (this lane covers 16 cols of its side)
    float h[16];
    #pragma unroll
    for (int i = 0; i < 8; ++i) { h[2*i] = a8[i].x; h[2*i+1] = a8[i].y; }
    const float4* bf = (const float4*)(ft_b  + col);
    const float4* bg = (const float4*)(fft_b + col);
    const float4* wp = (const float4*)(out_w + side * FT_OUT + col);
    float p = 0.f;
    #pragma unroll
    for (int q = 0; q < 4; ++q) {
        float4 b = bf[q], gq = bg[q], w = wp[q];
        p += fminf(fmaxf(h[4*q+0] + b.x + gq.x, 0.f), 1.f) * w.x;
        p += fminf(fmaxf(h[4*q+1] + b.y + gq.y, 0.f), 1.f) * w.y;
        p += fminf(fmaxf(h[4*q+2] + b.z + gq.z, 0.f), 1.f) * w.z;
        p += fminf(fmaxf(h[4*q+3] + b.w + gq.w, 0.f), 1.f) * w.w;
    }
    p += __shfl_xor(p, 1, 64);
    p += __shfl_xor(p, 2, 64);
    p += __shfl_xor(p, 4, 64);
    if (active && ql == 0)
        partial[(size_t)slice * n_boards + board] = p;
}

// ---------- final: sum 4 partials + sigmoid ----------
__global__ __launch_bounds__(256) void nnue_final(
    const float* __restrict__ partial, const float* __restrict__ out_b,
    float* __restrict__ out, int n)
{
    int b = blockIdx.x * blockDim.x + threadIdx.x;
    if (b >= n) return;
    float zv = out_b[0];
    #pragma unroll
    for (int s = 0; s < NSLICE; ++s) zv += partial[(size_t)s * n + b];
    out[b] = 1.0f / (1.0f + expf(-zv));
}

// ---------- fallback: direct f32 gather (if ws too small) ----------
__global__ __launch_bounds__(256) void nnue_fwd_direct(
    const int* __restrict__ stm_idx, const int* __restrict__ nstm_idx,
    const int* __restrict__ f_stm_idx, const int* __restrict__ f_nstm_idx,
    const float* __restrict__ ft_w, const float* __restrict__ ft_b,
    const float* __restrict__ fft_w, const float* __restrict__ fft_b,
    const float* __restrict__ out_w, const float* __restrict__ out_b,
    float* __restrict__ out, int n_boards)
{
    const int board = (int)((blockIdx.x * blockDim.x + threadIdx.x) >> 6);
    const int lane  = (int)(threadIdx.x & 63);
    if (board >= n_boards) return;
    const int col = lane << 2;
    const float4 ftb  = *(const float4*)(ft_b  + col);
    const float4 fftb = *(const float4*)(fft_b + col);
    float a0x = ftb.x + fftb.x, a0y = ftb.y + fftb.y,
          a0z = ftb.z + fftb.z, a0w = ftb.w + fftb.w;
    float a1x = a0x, a1y = a0y, a1z = a0z, a1w = a0w;
    const int* si  = stm_idx    + (size_t)board * NA;
    const int* ni  = nstm_idx   + (size_t)board * NA;
    const int* fsi = f_stm_idx  + (size_t)board * NA;
    const int* fni = f_nstm_idx + (size_t)board * NA;
    #pragma unroll 5
    for (int a = 0; a < NA; ++a) {
        const float4 r0 = *(const float4*)(ft_w  + (size_t)si[a]  * FT_OUT + col);
        const float4 r1 = *(const float4*)(ft_w  + (size_t)ni[a]  * FT_OUT + col);
        const float4 r2 = *(const float4*)(fft_w + (size_t)fsi[a] * FT_OUT + col);
        const float4 r3 = *(const float4*)(fft_w + (size_t)fni[a] * FT_OUT + col);
        a0x += r0.x + r2.x; a0y += r0.y + r2.y; a0z += r0.z + r2.z; a0w += r0.w + r2.w;
        a1x += r1.x + r3.x; a1y += r1.y + r3.y; a1z += r1.z + r3.z; a1w += r1.w + r3.w;
    }
    a0x = fminf(fmaxf(a0x, 0.f), 1.f); a0y = fminf(fmaxf(a0y, 0.f), 1.f);
    a0z = fminf(fmaxf(a0z, 0.f), 1.f); a0w = fminf(fmaxf(a0w, 0.f), 1.f);
    a1x = fminf(fmaxf(a1x, 0.f), 1.f); a1y = fminf(fmaxf(a1y, 0.f), 1.f);
    a1z = fminf(fmaxf(a1z, 0.f), 1.f); a1w = fminf(fmaxf(a1w, 0.f), 1.f);
    const float4 w0 = *(const float4*)(out_w + col);
    const float4 w1 = *(const float4*)(out_w + FT_OUT + col);
    float p = a0x * w0.x + a0y * w0.y + a0z * w0.z + a0w * w0.w
            + a1x * w1.x + a1y * w1.y + a1z * w1.z + a1w * w1.w;
    #pragma unroll
    for (int off = 32; off > 0; off >>= 1) p += __shfl_down(p, off, 64);
    if (lane == 0) out[board] = 1.0f / (1.0f + expf(-(p + out_b[0])));
}

extern "C" void kernel_launch(void* const* d_in, const int* in_sizes, int n_in,
                              void* d_out, int out_size, void* d_ws, size_t ws_size,
                              hipStream_t stream) {
    const int*   stm_idx    = (const int*)d_in[0];
    const int*   nstm_idx   = (const int*)d_in[1];
    const int*   f_stm_idx  = (const int*)d_in[2];
    const int*   f_nstm_idx = (const int*)d_in[3];
    const float* ft_w  = (const float*)d_in[4];
    const float* ft_b  = (const float*)d_in[5];
    const float* fft_w = (const float*)d_in[6];
    const float* fft_b = (const float*)d_in[7];
    const float* out_w = (const float*)d_in[8];
    const float* out_b = (const float*)d_in[9];
    float* out = (float*)d_out;

    const int n_boards = in_sizes[0] / NA;

    const size_t ft_bytes   = (size_t)FT_IN  * FT_OUT;                   // 10.49 MB fp8
    const size_t fft_bytes  = (size_t)FFT_IN * FT_OUT;                   // 160 KB fp8
    const size_t pidx_bytes = (size_t)n_boards * NA * sizeof(uint2);     // 3.93 MB
    const size_t part_bytes = (size_t)n_boards * NSLICE * sizeof(float); // 256 KB
    const size_t need = ft_bytes + fft_bytes + pidx_bytes + part_bytes;

    const size_t lds_bytes = (size_t)NA * BPB * 8 + (size_t)FFT_IN * 64; // 71680

    bool ok = (ws_size >= need);
    if (ok) {
        ok = (hipFuncSetAttribute((const void*)nnue_gather,
                                  hipFuncAttributeMaxDynamicSharedMemorySize,
                                  (int)lds_bytes) == hipSuccess);
    }
    if (!ok) {
        const int grid = (n_boards + 3) / 4;
        nnue_fwd_direct<<<grid, 256, 0, stream>>>(stm_idx, nstm_idx, f_stm_idx, f_nstm_idx,
                                                  ft_w, ft_b, fft_w, fft_b, out_w, out_b,
                                                  out, n_boards);
        return;
    }

    char* wsp = (char*)d_ws;
    uint4* ws_ft   = (uint4*)wsp;               wsp += ft_bytes;
    uint4* ws_fft  = (uint4*)wsp;               wsp += fft_bytes;
    uint2* ws_pidx = (uint2*)wsp;               wsp += pidx_bytes;
    float* ws_part = (float*)wsp;

    {   // fused prep: fp8 converts + streaming index pack in one dispatch
        const int nb_ft   = FT_IN  * 16 / 256;               // 2560
        const int nb_fft  = FFT_IN * 16 / 256;               // 40
        const int nb_pack = (n_boards * NA + 255) / 256;
        prep<<<nb_ft + nb_fft + nb_pack, 256, 0, stream>>>(
            ft_w, fft_w, stm_idx, nstm_idx, f_stm_idx, f_nstm_idx,
            ws_ft, ws_fft, ws_pidx, n_boards, nb_ft, nb_fft);
    }
    {   // sliced gather: slice = blockIdx&3 pins each 2.62 MB ft slice to 2 XCDs' L2
        int groups = (n_boards + BPB - 1) / BPB;
        nnue_gather<<<groups * NSLICE, 1024, lds_bytes, stream>>>(
            (const uint2*)ws_pidx, (const char*)ws_ft, (const char*)ws_fft,
            ft_b, fft_b, out_w, ws_part, n_boards);
    }
    {   // reduce partials + sigmoid
        nnue_final<<<(n_boards + 255) / 256, 256, 0, stream>>>(ws_part, out_b, out, n_boards);
    }
}